// Round 7
// baseline (380.967 us; speedup 1.0000x reference)
//
#include <hip/hip_runtime.h>
#include <math.h>

typedef unsigned int u32;
typedef unsigned short u16;

#define B_  2
#define S_  2048
#define D_  1024
#define H_  16
#define DK_ 64
#define FF_ 4096
#define NEG_ -1000000000.0f

typedef __attribute__((ext_vector_type(8))) short short8;
typedef __attribute__((ext_vector_type(4))) float floatx4;
typedef __attribute__((ext_vector_type(4))) unsigned short ushort4_t;

__device__ inline u16 f2b(float f) {
    union { float f; u32 u; } v; v.f = f;
    u32 r = (v.u + 0x7fffu + ((v.u >> 16) & 1u)) >> 16;
    return (u16)r;
}
__device__ inline float b2f(u16 b) {
    union { u32 u; float f; } v; v.u = ((u32)b) << 16;
    return v.f;
}

__device__ inline void gl_lds16(const u16* g, u16* l) {
    __builtin_amdgcn_global_load_lds((const __attribute__((address_space(1))) u32*)g,
                                     (__attribute__((address_space(3))) u32*)l, 16, 0, 0);
}

// ------- 4x square (1024x1024) weight transpose+convert in one launch -------
__global__ void tconv4(const float* __restrict__ W0, const float* __restrict__ W1_,
                       const float* __restrict__ W2_, const float* __restrict__ W3,
                       u16* __restrict__ dstBase) {
    __shared__ float tile[32][33];
    int z = blockIdx.z;
    const float* Wm = (z == 0) ? W0 : (z == 1) ? W1_ : (z == 2) ? W2_ : W3;
    u16* Wt = dstBase + (size_t)z * 1024 * 1024;
    const int K = 1024, N = 1024;
    int n0 = blockIdx.x * 32, k0 = blockIdx.y * 32;
    int tx = threadIdx.x & 31, ty = threadIdx.x >> 5;
#pragma unroll
    for (int r = 0; r < 32; r += 8)
        tile[ty + r][tx] = Wm[(size_t)(k0 + ty + r) * N + n0 + tx];
    __syncthreads();
#pragma unroll
    for (int r = 0; r < 32; r += 8)
        Wt[(size_t)(n0 + ty + r) * K + k0 + tx] = f2b(tile[tx][ty + r]);
}

// ------- FFN weights: z=0 -> W1 (K=1024,N=4096), z=1 -> W2 (K=4096,N=1024) -------
__global__ void tconvFF(const float* __restrict__ W1_, const float* __restrict__ W2_,
                        u16* __restrict__ Wt1, u16* __restrict__ Wt2) {
    __shared__ float tile[32][33];
    int z = blockIdx.z;
    const float* Wm = z ? W2_ : W1_;
    u16* Wt = z ? Wt2 : Wt1;
    int K = z ? 4096 : 1024, N = z ? 1024 : 4096;
    int n0 = (z ? blockIdx.y : blockIdx.x) * 32;
    int k0 = (z ? blockIdx.x : blockIdx.y) * 32;
    int tx = threadIdx.x & 31, ty = threadIdx.x >> 5;
#pragma unroll
    for (int r = 0; r < 32; r += 8)
        tile[ty + r][tx] = Wm[(size_t)(k0 + ty + r) * N + n0 + tx];
    __syncthreads();
#pragma unroll
    for (int r = 0; r < 32; r += 8)
        Wt[(size_t)(n0 + ty + r) * K + k0 + tx] = f2b(tile[tx][ty + r]);
}

__global__ void catbias(const float* __restrict__ bq, const float* __restrict__ bk,
                        const float* __restrict__ bv, float* __restrict__ out) {
    int i = blockIdx.x * 256 + threadIdx.x;
    float v = (i < 1024) ? bq[i] : (i < 2048) ? bk[i - 1024] : bv[i - 2048];
    out[i] = v;
}

// ---- mask tile reduction: tflag[it][jt] = all(mask[128it..][128jt..] != 0) ----
__global__ __launch_bounds__(256)
void mask_tiles(const int* __restrict__ mask, int* __restrict__ tflag) {
    int jt = blockIdx.x, it = blockIdx.y;
    const int* base = mask + (size_t)it * 128 * S_ + jt * 128;
    int t = threadIdx.x;
    int ok = 1;
    for (int e = t; e < 128 * 32; e += 256) {
        int r = e >> 5, c4 = e & 31;
        int4 vv = *(const int4*)&base[(size_t)r * S_ + c4 * 4];
        ok &= (vv.x != 0) & (vv.y != 0) & (vv.z != 0) & (vv.w != 0);
    }
    ok = (int)__all(ok);
    __shared__ int red[4];
    if ((t & 63) == 0) red[t >> 6] = ok;
    __syncthreads();
    if (t == 0) tflag[it * 16 + jt] = red[0] & red[1] & red[2] & red[3];
}

// ---------------- LayerNorm -> bf16 out ----------------
__global__ void ln_bf16(const float* __restrict__ x, const float* __restrict__ g,
                        const float* __restrict__ b, u16* __restrict__ out) {
    int row = blockIdx.x;
    int t = threadIdx.x;
    const float* xr = x + (size_t)row * D_;
    __shared__ float red[256];

    float v[4];
    float s = 0.f;
#pragma unroll
    for (int i = 0; i < 4; i++) { v[i] = xr[i * 256 + t]; s += v[i]; }
    red[t] = s; __syncthreads();
    for (int off = 128; off > 0; off >>= 1) {
        if (t < off) red[t] += red[t + off];
        __syncthreads();
    }
    float mu = red[0] * (1.0f / D_);
    __syncthreads();

    float vs = 0.f;
#pragma unroll
    for (int i = 0; i < 4; i++) { float d = v[i] - mu; vs += d * d; }
    red[t] = vs; __syncthreads();
    for (int off = 128; off > 0; off >>= 1) {
        if (t < off) red[t] += red[t + off];
        __syncthreads();
    }
    float rstd = rsqrtf(red[0] * (1.0f / D_) + 1e-5f);

    u16* outr = out + (size_t)row * D_;
#pragma unroll
    for (int i = 0; i < 4; i++) {
        int col = i * 256 + t;
        outr[col] = f2b((v[i] - mu) * rstd * g[col] + b[col]);
    }
}

// ---- fused split-K merge + residual + bias + LayerNorm (for Wo path) ----
__global__ __launch_bounds__(256)
void merge_ln(const u16* __restrict__ P, const float* __restrict__ x,
              const float* __restrict__ bo, const float* __restrict__ g,
              const float* __restrict__ bl, float* __restrict__ x1,
              u16* __restrict__ n2) {
    const size_t MN = (size_t)B_ * S_ * D_;
    int row = blockIdx.x, t = threadIdx.x;
    size_t base = (size_t)row * D_;
    __shared__ float red[256];

    float v[4];
    float s = 0.f;
#pragma unroll
    for (int i = 0; i < 4; i++) {
        int col = i * 256 + t;
        float val = x[base + col] + bo[col] + b2f(P[base + col]) + b2f(P[MN + base + col]);
        v[i] = val; s += val;
    }
    red[t] = s; __syncthreads();
    for (int off = 128; off > 0; off >>= 1) {
        if (t < off) red[t] += red[t + off];
        __syncthreads();
    }
    float mu = red[0] * (1.0f / D_);
    __syncthreads();

    float vs = 0.f;
#pragma unroll
    for (int i = 0; i < 4; i++) { float d = v[i] - mu; vs += d * d; }
    red[t] = vs; __syncthreads();
    for (int off = 128; off > 0; off >>= 1) {
        if (t < off) red[t] += red[t + off];
        __syncthreads();
    }
    float rstd = rsqrtf(red[0] * (1.0f / D_) + 1e-5f);

#pragma unroll
    for (int i = 0; i < 4; i++) {
        int col = i * 256 + t;
        x1[base + col] = v[i];
        n2[base + col] = f2b((v[i] - mu) * rstd * g[col] + bl[col]);
    }
}

// ---------------- bf16 MFMA GEMM, cross-iteration prefetch double-buffer ---------
// EPI 0: bf16 QKV scatter (Q pre-scaled by 1/8); 1: fp32+residual; 2: bf16 GELU; 3: bf16 partial
template <int EPI>
__global__ __launch_bounds__(256, 4)
void gemm_bt(const u16* __restrict__ A, const u16* __restrict__ Bt,
             const float* __restrict__ bias, const float* __restrict__ R,
             void* __restrict__ Cv, int M, int N, int K, int ldA, int ldB) {
    __shared__ u16 As[2][128 * 32];
    __shared__ u16 Bs[2][128 * 32];
    int tid = threadIdx.x;
    int lane = tid & 63, w = tid >> 6;
    int wm = w >> 1, wn = w & 1;
    int m0 = blockIdx.x * 128, n0 = blockIdx.y * 128;
    size_t koff = (size_t)blockIdx.z * K;

    floatx4 acc[4][4];
#pragma unroll
    for (int a = 0; a < 4; a++)
#pragma unroll
        for (int b2 = 0; b2 < 4; b2++) acc[a][b2] = (floatx4){0.f, 0.f, 0.f, 0.f};

    int r4 = lane >> 2;
    int qg = ((lane & 3) ^ ((lane >> 3) & 3)) * 8;
    const u16* Ag0 = A + (size_t)(m0 + w * 16 + r4) * ldA + koff + qg;
    const u16* Bg0 = Bt + (size_t)(n0 + w * 16 + r4) * ldB + koff + qg;
    const int ldsOff = (w * 16) * 32;

    int c = lane & 15, g = lane >> 4;
    int sw = (g ^ ((c >> 1) & 3)) * 8;

    const int nIter = K >> 5;

    gl_lds16(Ag0, &As[0][ldsOff]);
    gl_lds16(Ag0 + (size_t)64 * ldA, &As[0][ldsOff + 64 * 32]);
    gl_lds16(Bg0, &Bs[0][ldsOff]);
    gl_lds16(Bg0 + (size_t)64 * ldB, &Bs[0][ldsOff + 64 * 32]);

    for (int it = 0; it < nIter; it++) {
        __syncthreads();
        int cur = it & 1, nxt = cur ^ 1;
        if (it + 1 < nIter) {
            int kk = (it + 1) << 5;
            gl_lds16(Ag0 + kk, &As[nxt][ldsOff]);
            gl_lds16(Ag0 + kk + (size_t)64 * ldA, &As[nxt][ldsOff + 64 * 32]);
            gl_lds16(Bg0 + kk, &Bs[nxt][ldsOff]);
            gl_lds16(Bg0 + kk + (size_t)64 * ldB, &Bs[nxt][ldsOff + 64 * 32]);
        }
        short8 fa[4], fb[4];
#pragma unroll
        for (int a = 0; a < 4; a++)
            fa[a] = *(const short8*)&As[cur][(wm * 64 + a * 16 + c) * 32 + sw];
#pragma unroll
        for (int b2 = 0; b2 < 4; b2++)
            fb[b2] = *(const short8*)&Bs[cur][(wn * 64 + b2 * 16 + c) * 32 + sw];
#pragma unroll
        for (int a = 0; a < 4; a++)
#pragma unroll
            for (int b2 = 0; b2 < 4; b2++)
                acc[a][b2] = __builtin_amdgcn_mfma_f32_16x16x32_bf16(fa[a], fb[b2], acc[a][b2], 0, 0, 0);
    }

    int mb = m0 + wm * 64, nb = n0 + wn * 64;
#pragma unroll
    for (int a = 0; a < 4; a++) {
#pragma unroll
        for (int b2 = 0; b2 < 4; b2++) {
            int mrow = mb + a * 16 + g * 4;
            int ncol = nb + b2 * 16 + c;
            float bv = (EPI == 3) ? 0.f : bias[ncol];
#pragma unroll
            for (int r = 0; r < 4; r++) {
                int m = mrow + r;
                float vvv = acc[a][b2][r] + bv;
                if (EPI == 0) {
                    int which = ncol >> 10, col = ncol & 1023;
                    if (which == 0) vvv *= 0.125f;  // fold 1/sqrt(DK) into Q
                    int bb = m >> 11, ss = m & 2047, hh = col >> 6, dk = col & 63;
                    ((u16*)Cv)[(size_t)which * ((size_t)B_ * S_ * D_) +
                               ((((size_t)bb * H_ + hh) * S_) + ss) * DK_ + dk] = f2b(vvv);
                } else if (EPI == 1) {
                    ((float*)Cv)[(size_t)m * N + ncol] = vvv + R[(size_t)m * N + ncol];
                } else if (EPI == 2) {
                    float u = 0.79788456080286536f * fmaf(0.044715f * vvv, vvv * vvv, vvv);
                    float th = 1.f - 2.f / (1.f + __expf(2.f * u));
                    ((u16*)Cv)[(size_t)m * N + ncol] = f2b(0.5f * vvv * (1.f + th));
                } else {
                    ((u16*)Cv)[(size_t)blockIdx.z * M * N + (size_t)m * N + ncol] = f2b(vvv);
                }
            }
        }
    }
}

// ---------------- FFN2 split-K merge: out = x1 + bf2 + sum_z P[z] ----------------
__global__ __launch_bounds__(256)
void ffn2_merge(const u16* __restrict__ P, const float* __restrict__ x1,
                const float* __restrict__ bf2, float* __restrict__ out) {
    const size_t MN = (size_t)B_ * S_ * D_;
    int e = (blockIdx.x * 256 + threadIdx.x) * 4;
    float4 xv = *(const float4*)&x1[e];
    float4 bv = *(const float4*)&bf2[e & 1023];
    float o0 = xv.x + bv.x, o1 = xv.y + bv.y, o2 = xv.z + bv.z, o3 = xv.w + bv.w;
#pragma unroll
    for (int z = 0; z < 4; z++) {
        ushort4_t pv = *(const ushort4_t*)&P[z * MN + e];
        o0 += b2f(pv[0]); o1 += b2f(pv[1]); o2 += b2f(pv[2]); o3 += b2f(pv[3]);
    }
    *(float4*)&out[e] = (float4){o0, o1, o2, o3};
}

// ---------------- MFMA sparse strided attention v5: one barrier, zero-LDS scores --
// blockIdx.x = bh (XCD-locality: all tiles of a head on one XCD), blockIdx.y = i0 tile.
// Score MFMA frags read straight from global (L1-served); LDS only for Vt + wave-
// private P. V staged into registers at top, written + synced once before PV.
#define MAXB_ 14
__global__ __launch_bounds__(256)
void attn5(const u16* __restrict__ q, const u16* __restrict__ k,
           const u16* __restrict__ v, const int* __restrict__ mask,
           const int* __restrict__ tileOK, u16* __restrict__ ob) {
    __shared__ u16 sh[25600];            // 51,200 B
    u16* Vt = sh;                        // [64][200] V^T window
    u16* P  = sh + 12800;                // [64][200] probs (wave-private rows)

    const int bh = blockIdx.x;
    const int i0 = blockIdx.y * 64;
    const int b  = bh >> 4, h = bh & 15;
    const int t  = threadIdx.x;
    const int lane = t & 63, w = t >> 6;
    const int c = lane & 15, g = lane >> 4;
    const int g4 = g * 4;
    const int qloc16 = w * 16;

    const u16* qg = q + ((size_t)bh * S_ + i0) * DK_;
    const u16* kg = k + (size_t)bh * S_ * DK_;
    const u16* vg = v + (size_t)bh * S_ * DK_;

    const int wlo = (i0 >= 128) ? i0 - 128 : 0;
    const int wn  = i0 + 64 - wlo;             // 64 / 128 / 192
    const int nb  = (i0 >= 256) ? (i0 >> 7) - 1 : 0;
    const int jb0 = i0 & 127;
    const int dd0 = i0 - wlo;

    // uniform mask fast-path check
    bool allOK = true;
    {
        const int* rowf = tileOK + (i0 >> 7) * 16;
        int jt0 = wlo >> 7, jt1 = (i0 + 63) >> 7;
        for (int jt = jt0; jt <= jt1; jt++) allOK &= (rowf[jt] != 0);
        for (int m = 0; m < nb; m++) allOK &= (rowf[m] != 0);
    }

    // ---- V window -> registers (threads 0..191 hold one full V row each)
    short8 vr[8];
    if (t < 192) {
        if (t < wn) {
#pragma unroll
            for (int dc = 0; dc < 8; dc++)
                vr[dc] = *(const short8*)(vg + (size_t)(wlo + t) * 64 + dc * 8);
        } else {
#pragma unroll
            for (int dc = 0; dc < 8; dc++) vr[dc] = (short8){0,0,0,0,0,0,0,0};
        }
    }

    // ---- Q fragments (direct global)
    short8 qa0 = *(const short8*)(qg + (size_t)(qloc16 + c) * 64 + g * 8);
    short8 qa1 = *(const short8*)(qg + (size_t)(qloc16 + c) * 64 + 32 + g * 8);

    // ---- band scores -> sbr[m] (lane c holds score for query qloc16+c)
    float sbr[MAXB_];
#pragma unroll
    for (int m = 0; m < MAXB_; m++) {
        sbr[m] = NEG_;
        if (m < nb) {
            int jrow = jb0 + (m << 7) + qloc16 + c;
            short8 kv0 = *(const short8*)(kg + (size_t)jrow * 64 + g * 8);
            short8 kv1 = *(const short8*)(kg + (size_t)jrow * 64 + 32 + g * 8);
            float p = 0.f;
#pragma unroll
            for (int i = 0; i < 8; i++) {
                p += b2f((u16)qa0[i]) * b2f((u16)kv0[i]);
                p += b2f((u16)qa1[i]) * b2f((u16)kv1[i]);
            }
            p += __shfl_xor(p, 16);
            p += __shfl_xor(p, 32);
            if (!allOK && mask[(size_t)(i0 + qloc16 + c) * S_ + jrow] == 0) p = NEG_;
            sbr[m] = p;
        }
    }

    // ---- window scores via MFMA (B-frags direct from global; L1-served)
    floatx4 sc[12];
#pragma unroll
    for (int ct = 0; ct < 12; ct++) sc[ct] = (floatx4){0.f, 0.f, 0.f, 0.f};
#pragma unroll
    for (int ct = 0; ct < 12; ct++) {
        const u16* kr = kg + (size_t)(wlo + ct * 16 + c) * 64 + g * 8;
        short8 fb0 = *(const short8*)kr;
        short8 fb1 = *(const short8*)(kr + 32);
        sc[ct] = __builtin_amdgcn_mfma_f32_16x16x32_bf16(qa0, fb0, sc[ct], 0, 0, 0);
        sc[ct] = __builtin_amdgcn_mfma_f32_16x16x32_bf16(qa1, fb1, sc[ct], 0, 0, 0);
    }

    // ---- mask + softmax stats
#pragma unroll
    for (int ct = 0; ct < 12; ct++) {
        int cidx = ct * 16 + c;
        int j = wlo + cidx;
#pragma unroll
        for (int r = 0; r < 4; r++) {
            int qloc = qloc16 + g4 + r;
            int d = dd0 + qloc - cidx;
            bool ok = (d >= 0) && (d <= 128);
            if (ok && !allOK) ok = (mask[(size_t)(i0 + qloc) * S_ + j] != 0);
            sc[ct][r] = ok ? sc[ct][r] : NEG_;
        }
    }

    float mv[4], inv[4];
#pragma unroll
    for (int r = 0; r < 4; r++) {
        float bs[MAXB_];
#pragma unroll
        for (int m = 0; m < MAXB_; m++)
            bs[m] = (m < nb) ? __shfl(sbr[m], g4 + r, 64) : NEG_;
        float mm = -1e30f;
#pragma unroll
        for (int ct = 0; ct < 12; ct++) mm = fmaxf(mm, sc[ct][r]);
        mm = fmaxf(mm, __shfl_xor(mm, 1));
        mm = fmaxf(mm, __shfl_xor(mm, 2));
        mm = fmaxf(mm, __shfl_xor(mm, 4));
        mm = fmaxf(mm, __shfl_xor(mm, 8));
#pragma unroll
        for (int m = 0; m < MAXB_; m++)
            if (m < nb) mm = fmaxf(mm, bs[m]);
        float sum = 0.f;
#pragma unroll
        for (int ct = 0; ct < 12; ct++) {
            float e = __expf(sc[ct][r] - mm);
            sc[ct][r] = e;
            sum += e;
        }
        sum += __shfl_xor(sum, 1);
        sum += __shfl_xor(sum, 2);
        sum += __shfl_xor(sum, 4);
        sum += __shfl_xor(sum, 8);
#pragma unroll
        for (int m = 0; m < MAXB_; m++)
            if (m < nb) sum += __expf(bs[m] - mm);
        mv[r] = mm;
        inv[r] = 1.f / sum;
    }

    // ---- write P (wave-private rows) + Vt (from registers); single barrier
#pragma unroll
    for (int ct = 0; ct < 12; ct++)
#pragma unroll
        for (int r = 0; r < 4; r++)
            P[(qloc16 + g4 + r) * 200 + ct * 16 + c] = f2b(sc[ct][r]);
    if (t < 192) {
#pragma unroll
        for (int dc = 0; dc < 8; dc++)
#pragma unroll
            for (int i = 0; i < 8; i++)
                Vt[(dc * 8 + i) * 200 + t] = (u16)vr[dc][i];
    }
    __syncthreads();

    // ---- window PV via MFMA
    floatx4 o[4];
#pragma unroll
    for (int nt = 0; nt < 4; nt++) o[nt] = (floatx4){0.f, 0.f, 0.f, 0.f};
#pragma unroll
    for (int ks = 0; ks < 6; ks++) {
        short8 pa = *(const short8*)&P[(qloc16 + c) * 200 + ks * 32 + g * 8];
#pragma unroll
        for (int nt = 0; nt < 4; nt++) {
            short8 vb = *(const short8*)&Vt[(nt * 16 + c) * 200 + ks * 32 + g * 8];
            o[nt] = __builtin_amdgcn_mfma_f32_16x16x32_bf16(pa, vb, o[nt], 0, 0, 0);
        }
    }

    // ---- band PV via per-lane register loads (L2-local after XCD swizzle)
#pragma unroll
    for (int m = 0; m < MAXB_; m++) {
        if (m < nb) {
            int vbase = jb0 + (m << 7) + qloc16 + g4;
            u16 vv[4][4];
#pragma unroll
            for (int r = 0; r < 4; r++)
#pragma unroll
                for (int nt = 0; nt < 4; nt++)
                    vv[r][nt] = vg[(size_t)(vbase + r) * 64 + nt * 16 + c];
#pragma unroll
            for (int r = 0; r < 4; r++) {
                float bs = __shfl(sbr[m], g4 + r, 64);
                float pb = __expf(bs - mv[r]);
#pragma unroll
                for (int nt = 0; nt < 4; nt++)
                    o[nt][r] += pb * b2f(vv[r][nt]);
            }
        }
    }

    // ---- normalize + write [B,S,D] bf16
#pragma unroll
    for (int nt = 0; nt < 4; nt++) {
#pragma unroll
        for (int r = 0; r < 4; r++) {
            int qi = i0 + qloc16 + g4 + r;
            ob[((size_t)b * S_ + qi) * D_ + h * 64 + nt * 16 + c] = f2b(o[nt][r] * inv[r]);
        }
    }
}

extern "C" void kernel_launch(void* const* d_in, const int* in_sizes, int n_in,
                              void* d_out, int out_size, void* d_ws, size_t ws_size,
                              hipStream_t stream) {
    const float* x    = (const float*)d_in[0];
    const int*   mask = (const int*)  d_in[1];
    const float* Wq   = (const float*)d_in[2];
    const float* bq   = (const float*)d_in[3];
    const float* Wk   = (const float*)d_in[4];
    const float* bk   = (const float*)d_in[5];
    const float* Wv   = (const float*)d_in[6];
    const float* bv   = (const float*)d_in[7];
    const float* Wo   = (const float*)d_in[8];
    const float* bo   = (const float*)d_in[9];
    const float* W1   = (const float*)d_in[10];
    const float* bf1  = (const float*)d_in[11];
    const float* W2   = (const float*)d_in[12];
    const float* bf2  = (const float*)d_in[13];
    const float* g1   = (const float*)d_in[14];
    const float* bl1  = (const float*)d_in[15];
    const float* g2   = (const float*)d_in[16];
    const float* bl2  = (const float*)d_in[17];

    char* wsb = (char*)d_ws;
    const size_t MB = 1024 * 1024;
    u16*   WtQKV  = (u16*)(wsb + 0);          // 6 MB; WtO contiguous after
    u16*   WtO    = (u16*)(wsb + 6 * MB);     // 2 MB
    u16*   Wt1    = (u16*)(wsb + 8 * MB);     // 8 MB
    u16*   Wt2    = (u16*)(wsb + 16 * MB);    // 8 MB
    u16*   n1b    = (u16*)(wsb + 24 * MB);    // 8 MB (reused as n2b)
    u16*   qkv    = (u16*)(wsb + 32 * MB);    // 24 MB (dead after attn)
    u16*   obb    = (u16*)(wsb + 56 * MB);    // 8 MB (dead after Wo gemm)
    float* x1     = (float*)(wsb + 32 * MB);  // 16 MB over dead q|k (live thru merge)
    u16*   ff1b   = (u16*)(wsb + 48 * MB);    // 33.5 MB over dead v|obb
    u16*   Ppart  = (u16*)(wsb + 82 * MB);    // 32 MB: FFN2 4x bf16 partials
    u16*   PpartO = (u16*)(wsb + 82 * MB);    // 16 MB: Wo 2x partials (dead before FFN2)
    float* bcat   = (float*)(wsb + 114 * MB); // 12 KB
    int*   tflag  = (int*)(wsb + 115 * MB);   // 1 KB
    u16*   n2b    = n1b;

    const int M = B_ * S_;  // 4096
    const size_t SZ = (size_t)B_ * S_ * D_;

    // 0. mask tile flags, weight transpose + convert, bias concat
    mask_tiles<<<dim3(16, 16), 256, 0, stream>>>(mask, tflag);
    tconv4<<<dim3(32, 32, 4), 256, 0, stream>>>(Wq, Wk, Wv, Wo, WtQKV);
    tconvFF<<<dim3(128, 32, 2), 256, 0, stream>>>(W1, W2, Wt1, Wt2);
    catbias<<<12, 256, 0, stream>>>(bq, bk, bv, bcat);

    // 1. LN1 -> bf16
    ln_bf16<<<M, 256, 0, stream>>>(x, g1, bl1, n1b);

    // 2. fused QKV projection (N=3072) -> bf16 [B,H,S,DK] x3 (Q pre-scaled 1/8)
    gemm_bt<0><<<dim3(32, 24), 256, 0, stream>>>(n1b, WtQKV, bcat, nullptr, qkv,
                                                 M, 3072, 1024, 1024, 1024);

    // 3. sparse strided attention (MFMA) -> bf16 [B,S,D]; grid.x = bh for XCD locality
    attn5<<<dim3(32, 32), 256, 0, stream>>>(qkv, qkv + SZ, qkv + 2 * SZ, mask, tflag, obb);

    // 4. Wo split-K=2 partials, then fused merge(+x+bo) + LN2
    gemm_bt<3><<<dim3(32, 8, 2), 256, 0, stream>>>(obb, WtO, nullptr, nullptr, PpartO,
                                                   M, 1024, 512, 1024, 1024);
    merge_ln<<<M, 256, 0, stream>>>(PpartO, x, bo, g2, bl2, x1, n2b);

    // 6. ff1 = GELU(n2 @ W1 + bf1) -> bf16
    gemm_bt<2><<<dim3(32, 32), 256, 0, stream>>>(n2b, Wt1, bf1, nullptr, ff1b,
                                                 M, 4096, 1024, 1024, 1024);

    // 7. FFN2 split-K=4: partials -> merge (out = x1 + ff1 @ W2 + bf2)
    gemm_bt<3><<<dim3(32, 8, 4), 256, 0, stream>>>(ff1b, Wt2, nullptr, nullptr, Ppart,
                                                   M, 1024, 1024, 4096, 4096);
    ffn2_merge<<<(int)(SZ / 1024), 256, 0, stream>>>(Ppart, x1, bf2, (float*)d_out);
}